// Round 2
// baseline (762.682 us; speedup 1.0000x reference)
//
#include <hip/hip_runtime.h>
#include <hip/hip_bf16.h>

typedef __attribute__((ext_vector_type(8))) short short8;
typedef __attribute__((ext_vector_type(4))) float floatx4;
typedef __attribute__((ext_vector_type(8))) unsigned short ushortx8;

__device__ __forceinline__ float b2f(unsigned short u) {
    return __uint_as_float(((unsigned int)u) << 16);
}
__device__ __forceinline__ unsigned short f2b(float f) {
    __hip_bfloat16 b = __float2bfloat16(f);
    return *(unsigned short*)&b;
}
// elu(leaky_relu(x, 0.2)): x>=0 -> x ; x<0 -> expm1(0.2x)
__device__ __forceinline__ float act_elu_lrelu(float x) {
    return x >= 0.f ? x : expm1f(0.2f * x);
}

// ---------------------------------------------------------------------------
// row_ptr build from sorted adj_row
// ---------------------------------------------------------------------------
__global__ void build_rowptr(const int* __restrict__ row, int* __restrict__ rp,
                             int E, int N) {
    int e = blockIdx.x * blockDim.x + threadIdx.x;
    if (e >= E) return;
    int r = row[e];
    int rprev = (e == 0) ? -1 : row[e - 1];
    for (int q = rprev + 1; q <= r; ++q) rp[q] = e;
    if (e == E - 1) {
        for (int q = r + 1; q <= N; ++q) rp[q] = E;
    }
}

// ---------------------------------------------------------------------------
// One-shot W prep: all four W's -> bf16, transposed + XOR-swizzled, so GEMM
// staging is a pure linear vector copy.
// Layout: Wb[(n * (CIN/8) + (kc ^ (n&7))) * 8 + kr],  k = kc*8 + kr
// ---------------------------------------------------------------------------
__global__ __launch_bounds__(256) void wprep(
    const float* __restrict__ W1, const float* __restrict__ W2,
    const float* __restrict__ W3, const float* __restrict__ W4,
    unsigned short* __restrict__ B1, unsigned short* __restrict__ B2,
    unsigned short* __restrict__ B3, unsigned short* __restrict__ B4) {
    int i = blockIdx.x * 256 + threadIdx.x;
    const float* W;
    unsigned short* Wb;
    int CIN, COUT, idx;
    if (i < 32768) {
        W = W1; Wb = B1; CIN = 256; COUT = 128; idx = i;
    } else if (i < 49152) {
        W = W2; Wb = B2; CIN = 128; COUT = 128; idx = i - 32768;
    } else if (i < 57344) {
        W = W3; Wb = B3; CIN = 128; COUT = 64; idx = i - 49152;
    } else if (i < 59392) {
        W = W4; Wb = B4; CIN = 64; COUT = 32; idx = i - 57344;
    } else {
        return;
    }
    int k = idx / COUT, n = idx % COUT;
    int kc = k >> 3, kr = k & 7;
    Wb[((size_t)n * (CIN / 8) + (kc ^ (n & 7))) * 8 + kr] =
        (unsigned short)f2b(W[idx]);
}

// ---------------------------------------------------------------------------
// MFMA GEMM with fused input-BN. 512 threads, 128 rows/block.
// W staged in TWO COUT-halves (halves LDS -> full occupancy).
//   if NORM: reads raw H, normalizes per-column with stats (sums/sumsqs),
//            writes normalized H back IN PLACE, uses normalized bf16 A-frags.
// ---------------------------------------------------------------------------
template <int CIN, int COUT, bool NORM>
__global__ __launch_bounds__(512, 8) void gemm_mfma(
    float* H, const unsigned short* __restrict__ Wb,
    unsigned short* __restrict__ S, const float* __restrict__ st, float invN,
    int Nrows) {
    constexpr int CHALF = COUT / 2;
    constexpr int NCHUNK = CIN / 8;
    __shared__ short Wt[CIN * CHALF];

    int wave = threadIdx.x >> 6, lane = threadIdx.x & 63;
    int m = lane & 15, quad = lane >> 4;
    int r0 = blockIdx.x * 128 + wave * 16;
    int rowi = r0 + m;
    int rowc = rowi < Nrows ? rowi : (Nrows - 1);

    // A fragments: A[m][k=quad*8+j], fp32 -> bf16, all k-steps in registers
    short8 a[CIN / 32];
    const float* hrow = H + rowc * CIN;
#pragma unroll
    for (int ks = 0; ks < CIN / 32; ++ks) {
        int c0 = ks * 32 + quad * 8;
        const float* p = hrow + c0;
        floatx4 x0 = *(const floatx4*)p;
        floatx4 x1 = *(const floatx4*)(p + 4);
        if constexpr (NORM) {
            floatx4 s0 = *(const floatx4*)(st + c0);
            floatx4 s1 = *(const floatx4*)(st + c0 + 4);
            floatx4 q0 = *(const floatx4*)(st + CIN + c0);
            floatx4 q1 = *(const floatx4*)(st + CIN + c0 + 4);
#pragma unroll
            for (int j = 0; j < 4; ++j) {
                float mean = s0[j] * invN;
                float var = q0[j] * invN - mean * mean;
                x0[j] = (x0[j] - mean) * rsqrtf(fmaxf(var, 0.f) + 1e-5f);
                mean = s1[j] * invN;
                var = q1[j] * invN - mean * mean;
                x1[j] = (x1[j] - mean) * rsqrtf(fmaxf(var, 0.f) + 1e-5f);
            }
            if (rowi < Nrows) {
                float* op = H + rowi * CIN + c0;
                __builtin_nontemporal_store(x0, (floatx4*)op);
                __builtin_nontemporal_store(x1, (floatx4*)(op + 4));
            }
        }
        short8 t;
#pragma unroll
        for (int j = 0; j < 4; ++j) {
            t[j] = (short)f2b(x0[j]);
            t[4 + j] = (short)f2b(x1[j]);
        }
        a[ks] = t;
    }

#pragma unroll
    for (int h = 0; h < 2; ++h) {
        // stage this COUT-half of pre-swizzled bf16 W: linear 16B copies
        {
            constexpr int CHUNKS = CIN * CHALF / 8;  // short8 chunks
            const short8* src = (const short8*)(Wb + h * CIN * CHALF);
            short8* dst = (short8*)Wt;
            for (int i = threadIdx.x; i < CHUNKS; i += 512) dst[i] = src[i];
        }
        __syncthreads();

#pragma unroll
        for (int nt = 0; nt < CHALF / 16; ++nt) {
            floatx4 acc = {0.f, 0.f, 0.f, 0.f};
            int nn = nt * 16 + m;  // local col within half
#pragma unroll
            for (int ks = 0; ks < CIN / 32; ++ks) {
                int kc = ks * 4 + quad;
                short8 b =
                    *(const short8*)(&Wt[(nn * NCHUNK + (kc ^ (nn & 7))) * 8]);
                acc = __builtin_amdgcn_mfma_f32_16x16x32_bf16(a[ks], b, acc, 0,
                                                              0, 0);
            }
            int n = h * CHALF + nn;
            // C/D: col = lane&15, row = quad*4 + reg
#pragma unroll
            for (int reg = 0; reg < 4; ++reg) {
                int rr = r0 + quad * 4 + reg;
                if (rr < Nrows) S[rr * COUT + n] = f2b(acc[reg]);
            }
        }
        __syncthreads();
    }
}

// ---------------------------------------------------------------------------
// SpMM + activation + fused BN stats.
// 16B ushort8 gathers, 8-deep packets (8 outstanding gathers/lane).
// Per-thread stats accumulators live in thread-owned LDS slots (frees 16
// VGPRs -> stay under the 64-VGPR occupancy quantum).
// ---------------------------------------------------------------------------
template <int C>
__global__ __launch_bounds__(256, 8) void spmm_act_stats(
    const ushortx8* __restrict__ S8, const int* __restrict__ colIdx,
    const float* __restrict__ vals, const int* __restrict__ rowPtr,
    float* __restrict__ Ag, float* __restrict__ stats, int N) {
    constexpr int LPN = C / 8;      // lanes per node
    constexpr int NPB = 256 / LPN;  // nodes per block per sweep
    __shared__ float sh[NPB][2][C];
    int sub = threadIdx.x / LPN;
    int lc = threadIdx.x % LPN;

    // zero own slots (no sync needed: each thread owns sh[sub][*][lc*8..+7])
    float* st0 = &sh[sub][0][lc * 8];
    float* st1 = &sh[sub][1][lc * 8];
#pragma unroll
    for (int j = 0; j < 8; ++j) { st0[j] = 0.f; st1[j] = 0.f; }

    int ngroups = (N + NPB - 1) / NPB;
    for (int g = blockIdx.x; g < ngroups; g += gridDim.x) {
        int node = g * NPB + sub;
        if (node < N) {
            int e0 = rowPtr[node], e1 = rowPtr[node + 1];
            float acc[8];
#pragma unroll
            for (int j = 0; j < 8; ++j) acc[j] = 0.f;
            int e = e0;
            for (; e + 8 <= e1; e += 8) {
                int i0 = colIdx[e], i1 = colIdx[e + 1];
                int i2 = colIdx[e + 2], i3 = colIdx[e + 3];
                int i4 = colIdx[e + 4], i5 = colIdx[e + 5];
                int i6 = colIdx[e + 6], i7 = colIdx[e + 7];
                float v0 = vals[e], v1 = vals[e + 1];
                float v2 = vals[e + 2], v3 = vals[e + 3];
                float v4 = vals[e + 4], v5 = vals[e + 5];
                float v6 = vals[e + 6], v7 = vals[e + 7];
                ushortx8 g0 = S8[i0 * LPN + lc];
                ushortx8 g1 = S8[i1 * LPN + lc];
                ushortx8 g2 = S8[i2 * LPN + lc];
                ushortx8 g3 = S8[i3 * LPN + lc];
                ushortx8 g4 = S8[i4 * LPN + lc];
                ushortx8 g5 = S8[i5 * LPN + lc];
                ushortx8 g6 = S8[i6 * LPN + lc];
                ushortx8 g7 = S8[i7 * LPN + lc];
#pragma unroll
                for (int j = 0; j < 8; ++j)
                    acc[j] += v0 * b2f(g0[j]) + v1 * b2f(g1[j]) +
                              v2 * b2f(g2[j]) + v3 * b2f(g3[j]) +
                              v4 * b2f(g4[j]) + v5 * b2f(g5[j]) +
                              v6 * b2f(g6[j]) + v7 * b2f(g7[j]);
            }
            for (; e + 4 <= e1; e += 4) {
                int i0 = colIdx[e], i1 = colIdx[e + 1];
                int i2 = colIdx[e + 2], i3 = colIdx[e + 3];
                float v0 = vals[e], v1 = vals[e + 1];
                float v2 = vals[e + 2], v3 = vals[e + 3];
                ushortx8 g0 = S8[i0 * LPN + lc];
                ushortx8 g1 = S8[i1 * LPN + lc];
                ushortx8 g2 = S8[i2 * LPN + lc];
                ushortx8 g3 = S8[i3 * LPN + lc];
#pragma unroll
                for (int j = 0; j < 8; ++j)
                    acc[j] += v0 * b2f(g0[j]) + v1 * b2f(g1[j]) +
                              v2 * b2f(g2[j]) + v3 * b2f(g3[j]);
            }
            for (; e < e1; ++e) {
                int i0 = colIdx[e];
                float v0 = vals[e];
                ushortx8 g0 = S8[i0 * LPN + lc];
#pragma unroll
                for (int j = 0; j < 8; ++j) acc[j] += v0 * b2f(g0[j]);
            }
            floatx4 r0, r1;
#pragma unroll
            for (int j = 0; j < 4; ++j) {
                float a0 = act_elu_lrelu(acc[j]);
                float a1 = act_elu_lrelu(acc[4 + j]);
                r0[j] = a0;
                r1[j] = a1;
                st0[j] += a0;
                st1[j] += a0 * a0;
                st0[4 + j] += a1;
                st1[4 + j] += a1 * a1;
            }
            float* op = Ag + node * C + lc * 8;
            *(floatx4*)op = r0;
            *(floatx4*)(op + 4) = r1;
        }
    }

    __syncthreads();
    if (threadIdx.x < C) {
        int c = threadIdx.x;
        float t0 = 0.f, t1 = 0.f;
#pragma unroll 4
        for (int gg = 0; gg < NPB; ++gg) {
            t0 += sh[gg][0][c];
            t1 += sh[gg][1][c];
        }
        atomicAdd(&stats[c], t0);
        atomicAdd(&stats[C + c], t1);
    }
}

// ---------------------------------------------------------------------------
// Final-layer BN normalize in place (h4 has no following GEMM to fuse into)
// ---------------------------------------------------------------------------
template <int C>
__global__ __launch_bounds__(256) void bn_norm(
    float* __restrict__ Ag, const float* __restrict__ stats, int N) {
    constexpr int RPB = 256 / C;
    int c = threadIdx.x % C;
    int rg = threadIdx.x / C;
    float invN = 1.f / (float)N;
    float mean = stats[c] * invN;
    float var = stats[C + c] * invN - mean * mean;
    float inv = rsqrtf(fmaxf(var, 0.f) + 1e-5f);
    for (int r = blockIdx.x * RPB + rg; r < N; r += gridDim.x * RPB) {
        float x = Ag[(size_t)r * C + c];
        Ag[(size_t)r * C + c] = (x - mean) * inv;
    }
}

// ---------------------------------------------------------------------------
extern "C" void kernel_launch(void* const* d_in, const int* in_sizes, int n_in,
                              void* d_out, int out_size, void* d_ws,
                              size_t ws_size, hipStream_t stream) {
    const float* x = (const float*)d_in[0];
    const int* adj_row = (const int*)d_in[1];
    const int* adj_col = (const int*)d_in[2];
    const float* adj_vals = (const float*)d_in[3];
    const float* W1 = (const float*)d_in[4];
    const float* W2 = (const float*)d_in[5];
    const float* W3 = (const float*)d_in[6];
    const float* W4 = (const float*)d_in[7];

    int N = in_sizes[0] / 256;
    int E = in_sizes[1];

    // workspace carve: rp | stats | Wb1..4 | S(bf16)
    char* ws = (char*)d_ws;
    int* rp = (int*)ws;
    size_t off = (((size_t)(N + 1) * 4) + 255) & ~(size_t)255;
    float* stats = (float*)(ws + off);  // 4 layers x 256 floats
    off += 4 * 256 * sizeof(float);
    unsigned short* Wb1 = (unsigned short*)(ws + off); off += 32768 * 2;
    unsigned short* Wb2 = (unsigned short*)(ws + off); off += 16384 * 2;
    unsigned short* Wb3 = (unsigned short*)(ws + off); off += 8192 * 2;
    unsigned short* Wb4 = (unsigned short*)(ws + off); off += 2048 * 2;
    off = (off + 255) & ~(size_t)255;
    unsigned short* S = (unsigned short*)(ws + off);  // support, N*128 bf16

    hipMemsetAsync(stats, 0, 4 * 256 * sizeof(float), stream);
    build_rowptr<<<(E + 255) / 256, 256, 0, stream>>>(adj_row, rp, E, N);
    wprep<<<232, 256, 0, stream>>>(W1, W2, W3, W4, Wb1, Wb2, Wb3, Wb4);

    float* h1 = (float*)d_out;
    float* h2 = h1 + (size_t)N * 128;
    float* h3 = h2 + (size_t)N * 128;
    float* h4 = h3 + (size_t)N * 64;

    float invN = 1.f / (float)N;
    int gblk = (N + 127) / 128;
    auto sgrid = [](int N, int npb) {
        int ng = (N + npb - 1) / npb;
        return ng < 2048 ? ng : 2048;
    };

    // layer 1: 256 -> 128 (input x is not normalized)
    gemm_mfma<256, 128, false><<<gblk, 512, 0, stream>>>(
        (float*)x, Wb1, S, nullptr, invN, N);
    spmm_act_stats<128><<<sgrid(N, 16), 256, 0, stream>>>(
        (const ushortx8*)S, adj_col, adj_vals, rp, h1, stats + 0, N);

    // layer 2: 128 -> 128 (gemm normalizes h1 in place using stats0)
    gemm_mfma<128, 128, true><<<gblk, 512, 0, stream>>>(
        h1, Wb2, S, stats + 0, invN, N);
    spmm_act_stats<128><<<sgrid(N, 16), 256, 0, stream>>>(
        (const ushortx8*)S, adj_col, adj_vals, rp, h2, stats + 256, N);

    // layer 3: 128 -> 64
    gemm_mfma<128, 64, true><<<gblk, 512, 0, stream>>>(
        h2, Wb3, S, stats + 256, invN, N);
    spmm_act_stats<64><<<sgrid(N, 32), 256, 0, stream>>>(
        (const ushortx8*)S, adj_col, adj_vals, rp, h3, stats + 512, N);

    // layer 4: 64 -> 32
    gemm_mfma<64, 32, true><<<gblk, 512, 0, stream>>>(
        h3, Wb4, S, stats + 512, invN, N);
    spmm_act_stats<32><<<sgrid(N, 64), 256, 0, stream>>>(
        (const ushortx8*)S, adj_col, adj_vals, rp, h4, stats + 768, N);
    bn_norm<32><<<256, 256, 0, stream>>>(h4, stats + 768, N);
}

// Round 3
// 607.484 us; speedup vs baseline: 1.2555x; 1.2555x over previous
//
#include <hip/hip_runtime.h>
#include <hip/hip_bf16.h>

typedef __attribute__((ext_vector_type(8))) short short8;
typedef __attribute__((ext_vector_type(4))) float floatx4;
typedef __attribute__((ext_vector_type(8))) unsigned short ushortx8;

__device__ __forceinline__ float b2f(unsigned short u) {
    return __uint_as_float(((unsigned int)u) << 16);
}
__device__ __forceinline__ unsigned short f2b(float f) {
    __hip_bfloat16 b = __float2bfloat16(f);
    return *(unsigned short*)&b;
}
// elu(leaky_relu(x, 0.2)): x>=0 -> x ; x<0 -> expm1(0.2x)
__device__ __forceinline__ float act_elu_lrelu(float x) {
    return x >= 0.f ? x : expm1f(0.2f * x);
}

// async global->LDS 16B per lane; dest is wave-uniform base + lane*16
__device__ __forceinline__ void gload16(const void* g, void* l) {
    __builtin_amdgcn_global_load_lds(
        (__attribute__((address_space(1))) void*)(g),
        (__attribute__((address_space(3))) void*)(l), 16, 0, 0);
}
#define SB() __builtin_amdgcn_sched_barrier(0)
#define WAITVM12()                                       \
    do {                                                 \
        asm volatile("s_waitcnt vmcnt(12)" ::: "memory"); \
        __builtin_amdgcn_sched_barrier(0);               \
    } while (0)

// ---------------------------------------------------------------------------
// row_ptr build from sorted adj_row
// ---------------------------------------------------------------------------
__global__ void build_rowptr(const int* __restrict__ row, int* __restrict__ rp,
                             int E, int N) {
    int e = blockIdx.x * blockDim.x + threadIdx.x;
    if (e >= E) return;
    int r = row[e];
    int rprev = (e == 0) ? -1 : row[e - 1];
    for (int q = rprev + 1; q <= r; ++q) rp[q] = e;
    if (e == E - 1) {
        for (int q = r + 1; q <= N; ++q) rp[q] = E;
    }
}

// ---------------------------------------------------------------------------
// One-shot W prep: all four W's -> bf16, transposed + XOR-swizzled.
// Layout: Wb[(n * (CIN/8) + (kc ^ (n&7))) * 8 + kr],  k = kc*8 + kr
// ---------------------------------------------------------------------------
__global__ __launch_bounds__(256) void wprep(
    const float* __restrict__ W1, const float* __restrict__ W2,
    const float* __restrict__ W3, const float* __restrict__ W4,
    unsigned short* __restrict__ B1, unsigned short* __restrict__ B2,
    unsigned short* __restrict__ B3, unsigned short* __restrict__ B4) {
    int i = blockIdx.x * 256 + threadIdx.x;
    const float* W;
    unsigned short* Wb;
    int CIN, COUT, idx;
    if (i < 32768) {
        W = W1; Wb = B1; CIN = 256; COUT = 128; idx = i;
    } else if (i < 49152) {
        W = W2; Wb = B2; CIN = 128; COUT = 128; idx = i - 32768;
    } else if (i < 57344) {
        W = W3; Wb = B3; CIN = 128; COUT = 64; idx = i - 49152;
    } else if (i < 59392) {
        W = W4; Wb = B4; CIN = 64; COUT = 32; idx = i - 57344;
    } else {
        return;
    }
    int k = idx / COUT, n = idx % COUT;
    int kc = k >> 3, kr = k & 7;
    Wb[((size_t)n * (CIN / 8) + (kc ^ (n & 7))) * 8 + kr] =
        (unsigned short)f2b(W[idx]);
}

// ---------------------------------------------------------------------------
// MFMA GEMM with fused input-BN. 256 threads, 64 rows/block.
// W staged in TWO COUT-halves (halves LDS -> more blocks/CU).
// ---------------------------------------------------------------------------
template <int CIN, int COUT, bool NORM>
__global__ __launch_bounds__(256) void gemm_mfma(
    float* H, const unsigned short* __restrict__ Wb,
    unsigned short* __restrict__ S, const float* __restrict__ st, float invN,
    int Nrows) {
    constexpr int CHALF = COUT / 2;
    constexpr int NCHUNK = CIN / 8;
    __shared__ short Wt[CIN * CHALF];

    int wave = threadIdx.x >> 6, lane = threadIdx.x & 63;
    int m = lane & 15, quad = lane >> 4;
    int r0 = blockIdx.x * 64 + wave * 16;
    int rowi = r0 + m;
    int rowc = rowi < Nrows ? rowi : (Nrows - 1);

    // A fragments: A[m][k=quad*8+j], fp32 -> bf16, all k-steps in registers
    short8 a[CIN / 32];
    const float* hrow = H + (size_t)rowc * CIN;
#pragma unroll
    for (int ks = 0; ks < CIN / 32; ++ks) {
        int c0 = ks * 32 + quad * 8;
        const float* p = hrow + c0;
        floatx4 x0 = *(const floatx4*)p;
        floatx4 x1 = *(const floatx4*)(p + 4);
        if constexpr (NORM) {
            floatx4 s0 = *(const floatx4*)(st + c0);
            floatx4 s1 = *(const floatx4*)(st + c0 + 4);
            floatx4 q0 = *(const floatx4*)(st + CIN + c0);
            floatx4 q1 = *(const floatx4*)(st + CIN + c0 + 4);
#pragma unroll
            for (int j = 0; j < 4; ++j) {
                float mean = s0[j] * invN;
                float var = q0[j] * invN - mean * mean;
                x0[j] = (x0[j] - mean) * rsqrtf(fmaxf(var, 0.f) + 1e-5f);
                mean = s1[j] * invN;
                var = q1[j] * invN - mean * mean;
                x1[j] = (x1[j] - mean) * rsqrtf(fmaxf(var, 0.f) + 1e-5f);
            }
            if (rowi < Nrows) {
                float* op = H + (size_t)rowi * CIN + c0;
                __builtin_nontemporal_store(x0, (floatx4*)op);
                __builtin_nontemporal_store(x1, (floatx4*)(op + 4));
            }
        }
        short8 t;
#pragma unroll
        for (int j = 0; j < 4; ++j) {
            t[j] = (short)f2b(x0[j]);
            t[4 + j] = (short)f2b(x1[j]);
        }
        a[ks] = t;
    }

#pragma unroll
    for (int h = 0; h < 2; ++h) {
        // stage this COUT-half of pre-swizzled bf16 W: linear 16B copies
        {
            constexpr int CHUNKS = CIN * CHALF / 8;  // short8 chunks
            const short8* src = (const short8*)(Wb + h * CIN * CHALF);
            short8* dst = (short8*)Wt;
            for (int i = threadIdx.x; i < CHUNKS; i += 256) dst[i] = src[i];
        }
        __syncthreads();

#pragma unroll
        for (int nt = 0; nt < CHALF / 16; ++nt) {
            floatx4 acc = {0.f, 0.f, 0.f, 0.f};
            int nn = nt * 16 + m;  // local col within half
#pragma unroll
            for (int ks = 0; ks < CIN / 32; ++ks) {
                int kc = ks * 4 + quad;
                short8 b =
                    *(const short8*)(&Wt[(nn * NCHUNK + (kc ^ (nn & 7))) * 8]);
                acc = __builtin_amdgcn_mfma_f32_16x16x32_bf16(a[ks], b, acc, 0,
                                                              0, 0);
            }
            int n = h * CHALF + nn;
            // C/D: col = lane&15, row = quad*4 + reg
#pragma unroll
            for (int reg = 0; reg < 4; ++reg) {
                int rr = r0 + quad * 4 + reg;
                if (rr < Nrows) S[(size_t)rr * COUT + n] = f2b(acc[reg]);
            }
        }
        __syncthreads();
    }
}

// ---------------------------------------------------------------------------
// SpMM + activation + fused BN stats, async-pipelined gathers.
// Wave-private 2-slot LDS pipeline: per 4-edge batch, 4x global_load_lds
// (16B/lane, zero VGPRs in flight), colIdx prefetched 2 batches ahead,
// counted vmcnt(12) waits (one batch always in flight). Uniform wave loop
// (max row length over the wave's nodes; invalid edges clamped + val=0).
// ---------------------------------------------------------------------------
template <int C>
__global__ __launch_bounds__(256) void spmm_act_stats(
    const ushortx8* __restrict__ S8, const int* __restrict__ colIdx,
    const float* __restrict__ vals, const int* __restrict__ rowPtr,
    float* __restrict__ Ag, float* __restrict__ stats, int N) {
    constexpr int LPN = C / 8;      // lanes per node
    constexpr int NPB = 256 / LPN;  // nodes per block
    __shared__ char stage[4 * 2 * 4096];  // 4 waves x 2 slots x 4KB (32KB)

    int tid = threadIdx.x;
    int sub = tid / LPN;
    int lc = tid % LPN;
    int wave = tid >> 6;
    int lane = tid & 63;
    char* wbase = stage + wave * 8192;

    float s[8], s2[8];
#pragma unroll
    for (int j = 0; j < 8; ++j) { s[j] = 0.f; s2[j] = 0.f; }

    int ngroups = (N + NPB - 1) / NPB;
    for (int g = blockIdx.x; g < ngroups; g += gridDim.x) {
        int node = g * NPB + sub;
        int nc = node < N ? node : N - 1;
        int e0 = rowPtr[nc];
        int e1 = node < N ? rowPtr[nc + 1] : e0;
        int len = e1 - e0;
        int wl = len;
#pragma unroll
        for (int mm = LPN; mm < 64; mm <<= 1) {
            int o = __shfl_xor(wl, mm, 64);
            wl = o > wl ? o : wl;
        }
        int tmax = (wl + 3) >> 2;
        if (tmax == 0) continue;

        // clamp edge index to a valid in-row slot
        auto ce = [&](int i) {
            int q = i < e1 - 1 ? i : e1 - 1;
            return q > 0 ? q : 0;
        };

        float acc[8];
#pragma unroll
        for (int j = 0; j < 8; ++j) acc[j] = 0.f;

        // ---- prologue: mirror steady-state issue pattern exactly ----
        int c0t[4];  // cidx[0] (consumed immediately for gathers[0])
#pragma unroll
        for (int k = 0; k < 4; ++k) c0t[k] = colIdx[ce(e0 + k)];
        SB();
        int ca[4];  // cidx[1]
#pragma unroll
        for (int k = 0; k < 4; ++k) ca[k] = colIdx[ce(e0 + 4 + k)];
        SB();
#pragma unroll
        for (int k = 0; k < 4; ++k)  // gathers[0] -> slot 0
            gload16(&S8[(size_t)c0t[k] * LPN + lc], wbase + k * 1024);
        SB();
        float vc[4];  // vals[0]
#pragma unroll
        for (int k = 0; k < 4; ++k) vc[k] = vals[ce(e0 + k)];
        SB();

        // ---- steady loop ----
        for (int t = 0; t < tmax; ++t) {
            int slot = t & 1;
            int cb[4];  // cidx[t+2]
            int b2 = e0 + t * 4 + 8;
#pragma unroll
            for (int k = 0; k < 4; ++k) cb[k] = colIdx[ce(b2 + k)];
            SB();
            WAITVM12();  // cidx[t+1] (ca) arrived; gathers[t] still in flight
            char* dst = wbase + (slot ^ 1) * 4096;
#pragma unroll
            for (int k = 0; k < 4; ++k)  // gathers[t+1]
                gload16(&S8[(size_t)ca[k] * LPN + lc], dst + k * 1024);
            SB();
            float vn[4];  // vals[t+1]
            int b1 = e0 + t * 4 + 4;
#pragma unroll
            for (int k = 0; k < 4; ++k) vn[k] = vals[ce(b1 + k)];
            SB();
            WAITVM12();  // gathers[t] + vals[t] done; t+1 batch in flight
            const char* src = wbase + slot * 4096 + lane * 16;
            int b0 = e0 + t * 4;
#pragma unroll
            for (int k = 0; k < 4; ++k) {
                ushortx8 gk = *(const ushortx8*)(src + k * 1024);
                float v = (b0 + k < e1) ? vc[k] : 0.f;
#pragma unroll
                for (int j = 0; j < 8; ++j) acc[j] += v * b2f(gk[j]);
            }
#pragma unroll
            for (int k = 0; k < 4; ++k) { ca[k] = cb[k]; vc[k] = vn[k]; }
        }

        if (node < N) {
            floatx4 r0, r1;
#pragma unroll
            for (int j = 0; j < 4; ++j) {
                float a0 = act_elu_lrelu(acc[j]);
                float a1 = act_elu_lrelu(acc[4 + j]);
                r0[j] = a0;
                r1[j] = a1;
                s[j] += a0;
                s2[j] += a0 * a0;
                s[4 + j] += a1;
                s2[4 + j] += a1 * a1;
            }
            float* op = Ag + (size_t)node * C + lc * 8;
            *(floatx4*)op = r0;
            *(floatx4*)(op + 4) = r1;
        }
    }

    // block-level column reduce (reuse staging LDS; all waves done)
    __syncthreads();
    float* sh = (float*)stage;  // [2][NPB][C] = 16KB <= 32KB
#pragma unroll
    for (int j = 0; j < 8; ++j) {
        sh[(0 * NPB + sub) * C + lc * 8 + j] = s[j];
        sh[(1 * NPB + sub) * C + lc * 8 + j] = s2[j];
    }
    __syncthreads();
    if (tid < C) {
        float t0 = 0.f, t1 = 0.f;
        for (int gg = 0; gg < NPB; ++gg) {
            t0 += sh[(0 * NPB + gg) * C + tid];
            t1 += sh[(1 * NPB + gg) * C + tid];
        }
        atomicAdd(&stats[tid], t0);
        atomicAdd(&stats[C + tid], t1);
    }
}

// ---------------------------------------------------------------------------
// Final-layer BN normalize in place (h4 has no following GEMM to fuse into)
// ---------------------------------------------------------------------------
template <int C>
__global__ __launch_bounds__(256) void bn_norm(
    float* __restrict__ Ag, const float* __restrict__ stats, int N) {
    constexpr int RPB = 256 / C;
    int c = threadIdx.x % C;
    int rg = threadIdx.x / C;
    float invN = 1.f / (float)N;
    float mean = stats[c] * invN;
    float var = stats[C + c] * invN - mean * mean;
    float inv = rsqrtf(fmaxf(var, 0.f) + 1e-5f);
    for (int r = blockIdx.x * RPB + rg; r < N; r += gridDim.x * RPB) {
        float x = Ag[(size_t)r * C + c];
        Ag[(size_t)r * C + c] = (x - mean) * inv;
    }
}

// ---------------------------------------------------------------------------
extern "C" void kernel_launch(void* const* d_in, const int* in_sizes, int n_in,
                              void* d_out, int out_size, void* d_ws,
                              size_t ws_size, hipStream_t stream) {
    const float* x = (const float*)d_in[0];
    const int* adj_row = (const int*)d_in[1];
    const int* adj_col = (const int*)d_in[2];
    const float* adj_vals = (const float*)d_in[3];
    const float* W1 = (const float*)d_in[4];
    const float* W2 = (const float*)d_in[5];
    const float* W3 = (const float*)d_in[6];
    const float* W4 = (const float*)d_in[7];

    int N = in_sizes[0] / 256;
    int E = in_sizes[1];

    // workspace carve: rp | stats | Wb1..4 | S(bf16)
    char* ws = (char*)d_ws;
    int* rp = (int*)ws;
    size_t off = (((size_t)(N + 1) * 4) + 255) & ~(size_t)255;
    float* stats = (float*)(ws + off);  // 4 layers x 256 floats
    off += 4 * 256 * sizeof(float);
    unsigned short* Wb1 = (unsigned short*)(ws + off); off += 32768 * 2;
    unsigned short* Wb2 = (unsigned short*)(ws + off); off += 16384 * 2;
    unsigned short* Wb3 = (unsigned short*)(ws + off); off += 8192 * 2;
    unsigned short* Wb4 = (unsigned short*)(ws + off); off += 2048 * 2;
    off = (off + 255) & ~(size_t)255;
    unsigned short* S = (unsigned short*)(ws + off);  // support, N*128 bf16

    hipMemsetAsync(stats, 0, 4 * 256 * sizeof(float), stream);
    build_rowptr<<<(E + 255) / 256, 256, 0, stream>>>(adj_row, rp, E, N);
    wprep<<<232, 256, 0, stream>>>(W1, W2, W3, W4, Wb1, Wb2, Wb3, Wb4);

    float* h1 = (float*)d_out;
    float* h2 = h1 + (size_t)N * 128;
    float* h3 = h2 + (size_t)N * 128;
    float* h4 = h3 + (size_t)N * 64;

    float invN = 1.f / (float)N;
    int gblk = (N + 63) / 64;
    auto sgrid = [](int N, int npb) {
        int ng = (N + npb - 1) / npb;
        return ng < 2048 ? ng : 2048;
    };

    // layer 1: 256 -> 128 (input x is not normalized)
    gemm_mfma<256, 128, false><<<gblk, 256, 0, stream>>>(
        (float*)x, Wb1, S, nullptr, invN, N);
    spmm_act_stats<128><<<sgrid(N, 16), 256, 0, stream>>>(
        (const ushortx8*)S, adj_col, adj_vals, rp, h1, stats + 0, N);

    // layer 2: 128 -> 128 (gemm normalizes h1 in place using stats0)
    gemm_mfma<128, 128, true><<<gblk, 256, 0, stream>>>(
        h1, Wb2, S, stats + 0, invN, N);
    spmm_act_stats<128><<<sgrid(N, 16), 256, 0, stream>>>(
        (const ushortx8*)S, adj_col, adj_vals, rp, h2, stats + 256, N);

    // layer 3: 128 -> 64
    gemm_mfma<128, 64, true><<<gblk, 256, 0, stream>>>(
        h2, Wb3, S, stats + 256, invN, N);
    spmm_act_stats<64><<<sgrid(N, 32), 256, 0, stream>>>(
        (const ushortx8*)S, adj_col, adj_vals, rp, h3, stats + 512, N);

    // layer 4: 64 -> 32
    gemm_mfma<64, 32, true><<<gblk, 256, 0, stream>>>(
        h3, Wb4, S, stats + 512, invN, N);
    spmm_act_stats<32><<<sgrid(N, 64), 256, 0, stream>>>(
        (const ushortx8*)S, adj_col, adj_vals, rp, h4, stats + 768, N);
    bn_norm<32><<<256, 256, 0, stream>>>(h4, stats + 768, N);
}